// Round 3
// baseline (4025.486 us; speedup 1.0000x reference)
//
#include <hip/hip_runtime.h>

#define HW 17
#define NPIX 289

__device__ __forceinline__ float bperm(int a, float v) {
    return __int_as_float(__builtin_amdgcn_ds_bpermute(a, __float_as_int(v)));
}
__device__ __forceinline__ float max3f(float a, float b, float c) { return fmaxf(fmaxf(a, b), c); }
__device__ __forceinline__ float clampf(float v) { return fminf(fmaxf(v, -10.f), 10.f); }

// vertical 3-tap sum (u + 2x + d) and diff (d - u) via cross-lane shuffle
#define VPAIR(xv, V, D) { const float u_ = bperm(upA,(xv)); const float dn_ = bperm(dnA,(xv)); \
                          (V) = u_ + 2.f*(xv) + dn_; (D) = dn_ - u_; }

__global__ __launch_bounds__(256, 3)
void ca_kernel(const float* __restrict__ cell, const float* __restrict__ food,
               const float* __restrict__ w3, const float* __restrict__ b3,
               const float* __restrict__ w4, const float* __restrict__ b4,
               const int* __restrict__ steps_p, const int B,
               float* __restrict__ out_cell, float* __restrict__ out_food,
               float* __restrict__ out_cnt, float* __restrict__ out_abv)
{
    const int t    = threadIdx.x;
    const int lane = t & 63;
    const int wid  = blockIdx.x * (blockDim.x >> 6) + (t >> 6);
    const int bl   = lane / 17;                // 0..2 real, 3 dead
    const int r    = lane - bl * 17;
    const int batch = wid * 3 + bl;
    const bool active = (bl < 3) && (batch < B);
    const float am = active ? 1.f : 0.f;

    // vertical-neighbor shuffle addresses; out-of-range -> lane 63 (always zero)
    const int upA  = ((r >= 1)            ? (lane - 1) : 63) << 2;
    const int dnA  = ((r <= 15 && bl < 3) ? (lane + 1) : 63) << 2;
    const int up2A = ((r >= 2)            ? (lane - 2) : 63) << 2;
    const int dn2A = ((r <= 14 && bl < 3) ? (lane + 2) : 63) << 2;

    // ---- food load + copy-out ----
    const size_t fbase = (size_t)(active ? batch : 0) * NPIX + (size_t)r * HW;
    float f[HW];
    #pragma unroll
    for (int c = 0; c < HW; ++c) f[c] = active ? food[fbase + c] : 0.f;
    #pragma unroll
    for (int c = 0; c < HW; ++c) if (active) out_food[fbase + c] = f[c];

    // ---- scent: separable 5x5 [.25,.5,1,.5,.25]^2 minus .0625*corners ----
    float hf[HW];
    #pragma unroll
    for (int c = 0; c < HW; ++c) {
        float s = f[c];
        if (c >= 1)  s += 0.5f  * f[c - 1];
        if (c <= 15) s += 0.5f  * f[c + 1];
        if (c >= 2)  s += 0.25f * f[c - 2];
        if (c <= 14) s += 0.25f * f[c + 2];
        hf[c] = s;
    }
    float sc[HW];
    {
        float fu2[HW], fd2[HW];
        #pragma unroll
        for (int c = 0; c < HW; ++c) {
            float u1 = bperm(upA, hf[c]),  d1 = bperm(dnA, hf[c]);
            float u2 = bperm(up2A, hf[c]), d2 = bperm(dn2A, hf[c]);
            sc[c] = hf[c] + 0.5f * (u1 + d1) + 0.25f * (u2 + d2);
            fu2[c] = bperm(up2A, f[c]);
            fd2[c] = bperm(dn2A, f[c]);
        }
        #pragma unroll
        for (int c = 0; c < HW; ++c) {
            float corr = 0.f;
            if (c >= 2)  corr += fu2[c - 2] + fd2[c - 2];
            if (c <= 14) corr += fu2[c + 2] + fd2[c + 2];
            sc[c] = (sc[c] - 0.0625f * corr) * am;   // dead lanes exactly 0
        }
    }

    // ---- scent-channel sobel (constant across steps) ----
    float sx3[HW], sy3[HW];
    {
        float vS[HW + 2], dS[HW + 2];
        vS[0] = 0.f; vS[HW + 1] = 0.f; dS[0] = 0.f; dS[HW + 1] = 0.f;
        #pragma unroll
        for (int c = 0; c < HW; ++c) {
            float u = bperm(upA, sc[c]), d = bperm(dnA, sc[c]);
            vS[c + 1] = u + 2.f * sc[c] + d;
            dS[c + 1] = d - u;
        }
        #pragma unroll
        for (int c = 0; c < HW; ++c) {
            sx3[c] = 0.125f * (vS[c + 2] - vS[c]);
            sy3[c] = 0.125f * (dS[c] + 2.f * dS[c + 1] + dS[c + 2]);
        }
    }

    // ---- initial state (ch0..2 only; ch3 handled at the end) ----
    const size_t cb = (size_t)(active ? batch : 0) * (4 * NPIX) + (size_t)r * HW;
    float x0[HW], x1[HW], x2[HW];
    #pragma unroll
    for (int c = 0; c < HW; ++c) {
        x0[c] = active ? cell[cb + c] : 0.f;
        x1[c] = active ? cell[cb + NPIX + c] : 0.f;
        x2[c] = active ? cell[cb + 2 * NPIX + c] : 0.f;
    }

    const int steps = steps_p[0];

    for (int s = 0; s < steps; ++s) {
        const bool last = (s == steps - 1);
        float x3v[HW];   // only defined+used when `last`

        // ---- premask: maxpool3(x0) > 0.1 as a 17-bit per-lane mask ----
        unsigned pmask = 0u;
        {
            float rm[HW];
            #pragma unroll
            for (int c = 0; c < HW; ++c) {
                float a  = (c >= 1)  ? x0[c - 1] : 0.f;
                float b2 = (c <= 15) ? x0[c + 1] : 0.f;
                rm[c] = max3f(a, x0[c], b2);
            }
            #pragma unroll
            for (int c = 0; c < HW; ++c) {
                float pm = max3f(rm[c], bperm(upA, rm[c]), bperm(dnA, rm[c]));
                pmask |= (pm > 0.1f) ? (1u << c) : 0u;
            }
        }

        // ---- dense + sobel, per-pixel rolling over columns ----
        float vm0=0.f,dm0=0.f, vm1=0.f,dm1=0.f, vm2=0.f,dm2=0.f;
        float vc0,dc0, vc1,dc1, vc2,dc2, vp0,dp0, vp1,dp1, vp2,dp2;
        VPAIR(x0[0], vc0, dc0) VPAIR(x1[0], vc1, dc1) VPAIR(x2[0], vc2, dc2)
        VPAIR(x0[1], vp0, dp0) VPAIR(x1[1], vp1, dp1) VPAIR(x2[1], vp2, dp2)

        #pragma unroll
        for (int c = 0; c < HW; ++c) {
            const float sxa = 0.125f * (vp0 - vm0);
            const float sya = 0.125f * (dm0 + 2.f * dc0 + dp0);
            const float sxb = 0.125f * (vp1 - vm1);
            const float syb = 0.125f * (dm1 + 2.f * dc1 + dp1);
            const float sxc = 0.125f * (vp2 - vm2);
            const float syc = 0.125f * (dm2 + 2.f * dc2 + dp2);

            // prefetch next column's vertical pair (hides bperm latency under dense)
            float vn0=0.f,dn0=0.f, vn1=0.f,dn1=0.f, vn2=0.f,dn2=0.f;
            if (c + 2 < HW) {
                VPAIR(x0[c + 2], vn0, dn0)
                VPAIR(x1[c + 2], vn1, dn1)
                VPAIR(x2[c + 2], vn2, dn2)
            }

            float acc0 = b4[0], acc1 = b4[1], acc2 = b4[2], acc3 = b4[3];
            #pragma clang loop unroll_count(4)
            for (int o = 0; o < 16; ++o) {
                float h = b3[o];
                h += w3[o*12+0]  * x0[c];  h += w3[o*12+1]  * x1[c];
                h += w3[o*12+2]  * x2[c];  h += w3[o*12+3]  * sc[c];
                h += w3[o*12+4]  * sxa;    h += w3[o*12+5]  * sxb;
                h += w3[o*12+6]  * sxc;    h += w3[o*12+7]  * sx3[c];
                h += w3[o*12+8]  * sya;    h += w3[o*12+9]  * syb;
                h += w3[o*12+10] * syc;    h += w3[o*12+11] * sy3[c];
                h = fmaxf(h, 0.f);
                acc0 += w4[o]      * h;
                acc1 += w4[16 + o] * h;
                acc2 += w4[32 + o] * h;
                acc3 += w4[48 + o] * h;
            }

            x0[c] = (x0[c] + acc0) * am;   // masked: dead lanes must stay 0 (cross-lane postmax)
            x1[c] = x1[c] + acc1;          // gated to 0 below; never cross-read before that
            x2[c] = x2[c] + acc2;
            if (last) x3v[c] = sc[c] + acc3;

            vm0=vc0; dm0=dc0; vc0=vp0; dc0=dp0; vp0=vn0; dp0=dn0;
            vm1=vc1; dm1=dc1; vc1=vp1; dc1=dp1; vp1=vn1; dp1=dn1;
            vm2=vc2; dm2=dc2; vc2=vp2; dc2=dp2; vp2=vn2; dp2=dn2;
        }

        // ---- post maxpool on ungated xn0, then life gate ----
        {
            float rm[HW];
            #pragma unroll
            for (int c = 0; c < HW; ++c) {
                float a  = (c >= 1)  ? x0[c - 1] : 0.f;
                float b2 = (c <= 15) ? x0[c + 1] : 0.f;
                rm[c] = max3f(a, x0[c], b2);
            }
            #pragma unroll
            for (int c = 0; c < HW; ++c) {
                float pm = max3f(rm[c], bperm(upA, rm[c]), bperm(dnA, rm[c]));
                const bool L = ((pmask & (1u << c)) != 0u) && (pm > 0.1f);
                x0[c] = L ? clampf(x0[c]) : 0.f;
                x1[c] = L ? clampf(x1[c]) : 0.f;
                x2[c] = L ? clampf(x2[c]) : 0.f;
                if (last && active) out_cell[cb + 3 * NPIX + c] = L ? clampf(x3v[c]) : 0.f;
            }
        }
    }

    // ---- final outputs ----
    #pragma unroll
    for (int c = 0; c < HW; ++c) {
        if (active) {
            out_cell[cb + c]            = x0[c];
            out_cell[cb + NPIX + c]     = x1[c];
            out_cell[cb + 2 * NPIX + c] = x2[c];
            if (steps == 0) out_cell[cb + 3 * NPIX + c] = cell[cb + 3 * NPIX + c];
        }
    }

    float rs = 0.f, rc = 0.f;
    #pragma unroll
    for (int c = 0; c < HW; ++c) {
        rs += x0[c];
        rc += (x0[c] > 0.1f) ? 1.f : 0.f;
    }
    float ssum = rs, scnt = rc;
    for (int k = 1; k <= 16; ++k) {
        int a = ((lane + k) & 63) << 2;
        ssum += bperm(a, rs);
        scnt += bperm(a, rc);
    }
    if (active && r == 0) { out_cnt[batch] = ssum; out_abv[batch] = scnt; }
}

extern "C" void kernel_launch(void* const* d_in, const int* in_sizes, int n_in,
                              void* d_out, int out_size, void* d_ws, size_t ws_size,
                              hipStream_t stream) {
    const float* cell  = (const float*)d_in[0];
    const float* food  = (const float*)d_in[1];
    const float* w3    = (const float*)d_in[2];
    const float* b3    = (const float*)d_in[3];
    const float* w4    = (const float*)d_in[4];
    const float* b4    = (const float*)d_in[5];
    const int*   steps = (const int*)d_in[6];

    const int B = in_sizes[0] / (4 * NPIX);

    float* out      = (float*)d_out;
    float* out_cell = out;
    float* out_food = out      + (size_t)B * 4 * NPIX;
    float* out_cnt  = out_food + (size_t)B * NPIX;
    float* out_abv  = out_cnt  + (size_t)B;

    const int waves  = (B + 2) / 3;
    const int blocks = (waves + 3) / 4;
    hipLaunchKernelGGL(ca_kernel, dim3(blocks), dim3(256), 0, stream,
                       cell, food, w3, b3, w4, b4, steps, B,
                       out_cell, out_food, out_cnt, out_abv);
}